// Round 6
// baseline (913.458 us; speedup 1.0000x reference)
//
#include <hip/hip_runtime.h>

// voltageNN: 5-layer projected LSTM (H=256, P=1) over T=1000, B=128 + MLP head.
// R6: single fused kernel, 768 blocks x 128 threads (2 waves):
//   blocks [0,640): LSTM stage for (layer l = bid>>7, batch b = bid&127).
//     Wave w owns hidden units k in {2w,2w+1} (128 units, 2/lane) -- halves
//     per-wave issue AND the compiler's serialized cell chain (R3-R5 showed
//     the scheduler serializes whatever one wave computes; VGPR stuck at 40).
//     Cross-wave h exchange: DPP wave-reduce -> lane63 ds_write to parity
//     slot -> __syncthreads -> ds_read both slots + add.
//   blocks [640,768): MLP head stage for batch b = bid-640. Consumes layer-4
//     chunks via the same agent-scope flag protocol, accumulates seq4 @ W1^T
//     incrementally (removes the 81 us post-LSTM tail), then runs the tiny
//     100x100x100x1 epilogue and writes d_out.

#define LAYERS 5
#define TT 1000
#define BATCH 128
#define CH 40            // chunk length (divides TT; <= 64 for lane broadcast)
#define NCH (TT / CH)    // 25 chunks

#define LOG2E 1.4426950408889634f

__device__ __forceinline__ float fast_exp2(float x) {
#if __has_builtin(__builtin_amdgcn_exp2f)
  return __builtin_amdgcn_exp2f(x);
#else
  return __exp2f(x);
#endif
}
__device__ __forceinline__ float fast_rcp(float x) {
#if __has_builtin(__builtin_amdgcn_rcpf)
  return __builtin_amdgcn_rcpf(x);
#else
  return 1.0f / x;
#endif
}
__device__ __forceinline__ float fast_sigmoid(float z) {
  float e = fast_exp2(-LOG2E * z);
  return fast_rcp(1.0f + e);
}

template <int CTRL>
__device__ __forceinline__ float dpp_add(float v) {
  int moved = __builtin_amdgcn_update_dpp(0, __builtin_bit_cast(int, v),
                                          CTRL, 0xF, 0xF, false);
  return v + __builtin_bit_cast(float, moved);
}

// After this sequence lanes 48..63 hold the full wave64 sum (verified R4/R5:
// absmax==0 via readlane63). We consume the value from lane 63 only.
__device__ __forceinline__ float wave_sum_to_hi(float v) {
  v = dpp_add<0x128>(v);  // row_ror:8
  v = dpp_add<0x124>(v);  // row_ror:4
  v = dpp_add<0x122>(v);  // row_ror:2
  v = dpp_add<0x121>(v);  // row_ror:1
  v = dpp_add<0x142>(v);  // row_bcast:15
  v = dpp_add<0x143>(v);  // row_bcast:31
  return v;
}

__device__ __forceinline__ float lane_bcast(float v, int s) {
  return __builtin_bit_cast(float, __builtin_amdgcn_readlane(__builtin_bit_cast(int, v), s));
}

__global__ __launch_bounds__(128) void fused_pipeline_kernel(
    const float* __restrict__ x,     // [B, T]
    const float* __restrict__ Wih,   // [L, 1024]
    const float* __restrict__ Whh,   // [L, 1024]
    const float* __restrict__ bih,   // [L, 1024]
    const float* __restrict__ bhh,   // [L, 1024]
    const float* __restrict__ Whr,   // [L, 256]
    const float* __restrict__ W1, const float* __restrict__ b1,
    const float* __restrict__ W2, const float* __restrict__ b2,
    const float* __restrict__ W3, const float* __restrict__ b3,
    const float* __restrict__ W4, const float* __restrict__ b4,
    float* __restrict__ seq,         // [L, B, T] layer outputs (workspace)
    int* __restrict__ flags,         // [L, B] chunk progress counters
    float* __restrict__ out)         // [B]
{
  __shared__ float hx[2][2];    // [parity][wave] partial-h slots (LSTM path)
  __shared__ float shx[CH];     // staged h4 chunk (head path)
  __shared__ float sh[100];
  __shared__ float sh2[100];
  __shared__ float red[2];

  const int bid  = blockIdx.x;
  const int tid  = threadIdx.x;
  const int w    = tid >> 6;
  const int lane = tid & 63;

  if (bid < LAYERS * BATCH) {
    // ------------------------------------------------------------------ LSTM
    const int l = bid >> 7;
    const int b = bid & 127;

    // Wave w owns k in {2w, 2w+1}: unit j = k*64 + lane.  Weights pre-scaled
    // into the exp2 domain: sc = -log2e (sigmoid gates), -2log2e (tanh gate).
    float wix[4][2], whx[4][2], gb[4][2], whr[2], cc[2];
    const int base = l * 1024;
#pragma unroll
    for (int g = 0; g < 4; ++g) {
      const float sc = (g == 2) ? (-2.0f * LOG2E) : (-LOG2E);
#pragma unroll
      for (int k2 = 0; k2 < 2; ++k2) {
        int j = base + g * 256 + (2 * w + k2) * 64 + lane;
        wix[g][k2] = Wih[j] * sc;
        whx[g][k2] = Whh[j] * sc;
        gb[g][k2]  = (bih[j] + bhh[j]) * sc;
      }
    }
#pragma unroll
    for (int k2 = 0; k2 < 2; ++k2) {
      whr[k2] = Whr[l * 256 + (2 * w + k2) * 64 + lane];
      cc[k2] = 0.0f;
    }

    const float* in  = (l == 0) ? (x + b * TT) : (seq + ((l - 1) * BATCH + b) * TT);
    float*       outp = seq + (l * BATCH + b) * TT;
    int*       my_flag = flags + l * BATCH + b;
    const int* in_flag = flags + (l - 1) * BATCH + b;  // used only when l > 0

    float h = 0.0f;
    for (int c = 0; c < NCH; ++c) {
      if (l > 0) {  // each wave spins independently; flag is monotone
        while (__hip_atomic_load(in_flag, __ATOMIC_ACQUIRE,
                                 __HIP_MEMORY_SCOPE_AGENT) <= c)
          __builtin_amdgcn_s_sleep(2);
      }
      float xv = 0.0f;
      if (lane < CH) {
        if (l == 0)
          xv = in[c * CH + lane];
        else
          xv = __hip_atomic_load(in + c * CH + lane, __ATOMIC_RELAXED,
                                 __HIP_MEMORY_SCOPE_AGENT);
      }

      float outv = 0.0f;
      for (int s = 0; s < CH; ++s) {
        const float xs = lane_bcast(xv, s);
        float r = 0.0f;
#pragma unroll
        for (int k2 = 0; k2 < 2; ++k2) {
          float e0 = fast_exp2(fmaf(h, whx[0][k2], fmaf(xs, wix[0][k2], gb[0][k2])));
          float e1 = fast_exp2(fmaf(h, whx[1][k2], fmaf(xs, wix[1][k2], gb[1][k2])));
          float e2 = fast_exp2(fmaf(h, whx[2][k2], fmaf(xs, wix[2][k2], gb[2][k2])));
          float e3 = fast_exp2(fmaf(h, whx[3][k2], fmaf(xs, wix[3][k2], gb[3][k2])));
          float ig = fast_rcp(1.0f + e0);
          float fg = fast_rcp(1.0f + e1);
          float gg = fmaf(2.0f, fast_rcp(1.0f + e2), -1.0f);
          float og = fast_rcp(1.0f + e3);
          cc[k2] = fmaf(fg, cc[k2], ig * gg);
          float tE = fast_exp2(cc[k2] * (-2.0f * LOG2E));
          float tc = fmaf(2.0f, fast_rcp(1.0f + tE), -1.0f);
          r = fmaf(og * tc, whr[k2], r);
        }
        r = wave_sum_to_hi(r);          // lanes 48..63 hold this wave's total
        if (lane == 63) hx[s & 1][w] = r;
        __syncthreads();
        h = hx[s & 1][0] + hx[s & 1][1];  // wave-uniform h(t) in VGPR
        if (w == 0 && lane == s) outv = h;
      }

      if (w == 0) {
        if (lane < CH)
          __hip_atomic_store(outp + c * CH + lane, outv, __ATOMIC_RELAXED,
                             __HIP_MEMORY_SCOPE_AGENT);
        if (lane == 0)
          __hip_atomic_store(my_flag, c + 1, __ATOMIC_RELEASE,
                             __HIP_MEMORY_SCOPE_AGENT);
      }
    }
  } else {
    // ------------------------------------------------------------- MLP head
    const int b = bid - LAYERS * BATCH;
    const float* h4 = seq + (4 * BATCH + b) * TT;
    const int* f4 = flags + 4 * BATCH + b;

    float acc = 0.0f;  // thread tid accumulates output tid of layer 1 (tid<100)
    for (int c = 0; c < NCH; ++c) {
      while (__hip_atomic_load(f4, __ATOMIC_ACQUIRE,
                               __HIP_MEMORY_SCOPE_AGENT) <= c)
        __builtin_amdgcn_s_sleep(16);
      if (tid < CH)
        shx[tid] = __hip_atomic_load(h4 + c * CH + tid, __ATOMIC_RELAXED,
                                     __HIP_MEMORY_SCOPE_AGENT);
      __syncthreads();
      if (tid < 100) {
        const float* wr = W1 + tid * TT + c * CH;  // 160c-byte offset: 16B aligned
#pragma unroll
        for (int j = 0; j < CH; j += 4) {
          float4 v = *(const float4*)(wr + j);
          acc = fmaf(v.x, shx[j + 0], acc);
          acc = fmaf(v.y, shx[j + 1], acc);
          acc = fmaf(v.z, shx[j + 2], acc);
          acc = fmaf(v.w, shx[j + 3], acc);
        }
      }
      __syncthreads();  // protect shx before next chunk overwrites
    }

    if (tid < 100) sh[tid] = fast_sigmoid(acc + b1[tid]);
    __syncthreads();

    if (tid < 100) {
      float a = b2[tid];
      const float* wr = W2 + tid * 100;
      for (int k = 0; k < 100; ++k) a += wr[k] * sh[k];
      sh2[tid] = fast_sigmoid(a);
    }
    __syncthreads();

    if (tid < 100) {
      float a = b3[tid];
      const float* wr = W3 + tid * 100;
      for (int k = 0; k < 100; ++k) a += wr[k] * sh2[k];
      sh[tid] = fmaxf(a, 0.0f);
    }
    __syncthreads();

    float r = (tid < 100) ? sh[tid] * W4[tid] : 0.0f;
    r = wave_sum_to_hi(r);
    if (lane == 63) red[w] = r;
    __syncthreads();
    if (tid == 0) out[b] = red[0] + red[1] + b4[0];
  }
}

extern "C" void kernel_launch(void* const* d_in, const int* in_sizes, int n_in,
                              void* d_out, int out_size, void* d_ws, size_t ws_size,
                              hipStream_t stream) {
  const float* x   = (const float*)d_in[0];
  const float* Wih = (const float*)d_in[1];
  const float* Whh = (const float*)d_in[2];
  const float* bih = (const float*)d_in[3];
  const float* bhh = (const float*)d_in[4];
  const float* Whr = (const float*)d_in[5];
  const float* W1  = (const float*)d_in[6];
  const float* b1  = (const float*)d_in[7];
  const float* W2  = (const float*)d_in[8];
  const float* b2  = (const float*)d_in[9];
  const float* W3  = (const float*)d_in[10];
  const float* b3  = (const float*)d_in[11];
  const float* W4  = (const float*)d_in[12];
  const float* b4  = (const float*)d_in[13];

  float* seq   = (float*)d_ws;                       // [5][128][1000] f32 = 2.56 MB
  int*   flags = (int*)(seq + LAYERS * BATCH * TT);  // [5][128] int

  hipMemsetAsync(flags, 0, LAYERS * BATCH * sizeof(int), stream);
  fused_pipeline_kernel<<<LAYERS * BATCH + BATCH, 128, 0, stream>>>(
      x, Wih, Whh, bih, bhh, Whr, W1, b1, W2, b2, W3, b3, W4, b4,
      seq, flags, (float*)d_out);
}

// Round 7
// 735.026 us; speedup vs baseline: 1.2428x; 1.2428x over previous
//
#include <hip/hip_runtime.h>

// voltageNN: 5-layer projected LSTM (H=256, P=1) over T=1000, B=128 + MLP head.
// R7: back to the R5 dataflow (one wave per (layer,batch); cross-wave exchange
// per step is dead -- R6 cost ~900 cyc/step). Three changes:
//  1. sched_barrier(0) after the 16 exp2s each step: pins [gx|h-fmaf|exp2]
//     (48 mutually independent instrs) before any combine -- defeats the
//     pressure-minimizing scheduler that serialized the gate chains (R3-R5).
//  2. Montgomery-pair reciprocals: 5 rcp/unit -> 3 (pairs: 1 rcp + 3 mul).
//     Trans instrs/step 40 -> 32 (floor 320 -> 256 cyc). Products <= 2^10.
//  3. MLP head fused as pipeline stage 6: 128 single-wave blocks consume
//     layer-4 chunks via the flag protocol (kills the ~80 us serial tail).
// Grid: 640 LSTM blocks + 128 head blocks, all 64 threads.

#define LAYERS 5
#define TT 1000
#define BATCH 128
#define CH 40            // chunk length (divides TT; <= 64 for lane broadcast)
#define NCH (TT / CH)    // 25 chunks

#define LOG2E 1.4426950408889634f

__device__ __forceinline__ float fast_exp2(float x) {
#if __has_builtin(__builtin_amdgcn_exp2f)
  return __builtin_amdgcn_exp2f(x);
#else
  return __exp2f(x);
#endif
}
__device__ __forceinline__ float fast_rcp(float x) {
#if __has_builtin(__builtin_amdgcn_rcpf)
  return __builtin_amdgcn_rcpf(x);
#else
  return 1.0f / x;
#endif
}
__device__ __forceinline__ float fast_sigmoid(float z) {
  float e = fast_exp2(-LOG2E * z);
  return fast_rcp(1.0f + e);
}
__device__ __forceinline__ void sched_fence() {
#if __has_builtin(__builtin_amdgcn_sched_barrier)
  __builtin_amdgcn_sched_barrier(0);
#endif
}

template <int CTRL>
__device__ __forceinline__ float dpp_add(float v) {
  int moved = __builtin_amdgcn_update_dpp(0, __builtin_bit_cast(int, v),
                                          CTRL, 0xF, 0xF, false);
  return v + __builtin_bit_cast(float, moved);
}

// Wave64 total -> wave-uniform SGPR (verified absmax==0 since R4).
__device__ __forceinline__ float wave_sum_uniform(float v) {
  v = dpp_add<0x128>(v);  // row_ror:8
  v = dpp_add<0x124>(v);  // row_ror:4
  v = dpp_add<0x122>(v);  // row_ror:2
  v = dpp_add<0x121>(v);  // row_ror:1
  v = dpp_add<0x142>(v);  // row_bcast:15
  v = dpp_add<0x143>(v);  // row_bcast:31
  return __builtin_bit_cast(float, __builtin_amdgcn_readlane(__builtin_bit_cast(int, v), 63));
}

__device__ __forceinline__ float lane_bcast(float v, int s) {
  return __builtin_bit_cast(float, __builtin_amdgcn_readlane(__builtin_bit_cast(int, v), s));
}

__global__ __launch_bounds__(64, 1) void fused_pipeline_kernel(
    const float* __restrict__ x,     // [B, T]
    const float* __restrict__ Wih,   // [L, 1024]
    const float* __restrict__ Whh,   // [L, 1024]
    const float* __restrict__ bih,   // [L, 1024]
    const float* __restrict__ bhh,   // [L, 1024]
    const float* __restrict__ Whr,   // [L, 256]
    const float* __restrict__ W1, const float* __restrict__ b1,
    const float* __restrict__ W2, const float* __restrict__ b2,
    const float* __restrict__ W3, const float* __restrict__ b3,
    const float* __restrict__ W4, const float* __restrict__ b4,
    float* __restrict__ seq,         // [L, B, T] layer outputs (workspace)
    int* __restrict__ flags,         // [L, B] chunk progress counters
    float* __restrict__ out)         // [B]
{
  const int bid  = blockIdx.x;
  const int lane = threadIdx.x & 63;

  if (bid < LAYERS * BATCH) {
    // ------------------------------------------------------------------ LSTM
    const int l = bid >> 7;
    const int b = bid & 127;

    // Weights pre-scaled into the exp2 domain: sc = -log2e (sigmoid gates i,f,o),
    // -2log2e (tanh gate g). Unit j = k*64 + lane.
    float wix[4][4], whx[4][4], gb[4][4], whr[4], cc[4];
    const int base = l * 1024;
#pragma unroll
    for (int g = 0; g < 4; ++g) {
      const float sc = (g == 2) ? (-2.0f * LOG2E) : (-LOG2E);
#pragma unroll
      for (int k = 0; k < 4; ++k) {
        int j = base + g * 256 + k * 64 + lane;
        wix[g][k] = Wih[j] * sc;
        whx[g][k] = Whh[j] * sc;
        gb[g][k]  = (bih[j] + bhh[j]) * sc;
      }
    }
#pragma unroll
    for (int k = 0; k < 4; ++k) {
      whr[k] = Whr[l * 256 + k * 64 + lane];
      cc[k] = 0.0f;
    }

    // Per-k combine with Montgomery-pair rcp:
    //  ig=1/a0=q01*a1, fg=1/a1=q01*a0, og=1/a3=q23*a2, gg=(1-E2)/a2=(1-E2)*q23*a3
    auto combine = [&](const float (&E)[4][4]) -> float {
      float r = 0.0f;
#pragma unroll
      for (int k = 0; k < 4; ++k) {
        float a0 = 1.0f + E[0][k];
        float a1 = 1.0f + E[1][k];
        float a2 = 1.0f + E[2][k];
        float a3 = 1.0f + E[3][k];
        float q01 = fast_rcp(a0 * a1);
        float q23 = fast_rcp(a2 * a3);
        float ig = q01 * a1;
        float fg = q01 * a0;
        float og = q23 * a2;
        float gg = (1.0f - E[2][k]) * (q23 * a3);
        cc[k] = fmaf(fg, cc[k], ig * gg);
        float e4 = fast_exp2(cc[k] * (-2.0f * LOG2E));
        float q4 = fast_rcp(1.0f + e4);
        float tc = fmaf(2.0f, q4, -1.0f);
        r = fmaf(og * tc, whr[k], r);
      }
      return r;
    };

    const float* in  = (l == 0) ? (x + b * TT) : (seq + ((l - 1) * BATCH + b) * TT);
    float*      outp = seq + (l * BATCH + b) * TT;
    int*      my_flag = flags + l * BATCH + b;
    const int* in_flag = flags + (l - 1) * BATCH + b;  // used only when l > 0

    float h = 0.0f;
    for (int c = 0; c < NCH; ++c) {
      if (l > 0) {
        while (__hip_atomic_load(in_flag, __ATOMIC_ACQUIRE,
                                 __HIP_MEMORY_SCOPE_AGENT) <= c)
          __builtin_amdgcn_s_sleep(2);
      }
      float xv = 0.0f;
      if (lane < CH) {
        if (l == 0)
          xv = in[c * CH + lane];
        else
          xv = __hip_atomic_load(in + c * CH + lane, __ATOMIC_RELAXED,
                                 __HIP_MEMORY_SCOPE_AGENT);
      }

      float outv = 0.0f;
      float r_carry;
      {  // step 0: no pending reduce
        const float xs = lane_bcast(xv, 0);
        float E[4][4];
#pragma unroll
        for (int g = 0; g < 4; ++g)
#pragma unroll
          for (int k = 0; k < 4; ++k)
            E[g][k] = fast_exp2(fmaf(h, whx[g][k], fmaf(xs, wix[g][k], gb[g][k])));
        sched_fence();
        r_carry = combine(E);
      }
#pragma unroll 1
      for (int s = 1; s < CH; ++s) {
        const float xs = lane_bcast(xv, s);
        // gx-phase (h-independent) — may overlap the reduce below
        float gx[4][4];
#pragma unroll
        for (int g = 0; g < 4; ++g)
#pragma unroll
          for (int k = 0; k < 4; ++k)
            gx[g][k] = fmaf(xs, wix[g][k], gb[g][k]);
        // finish step s-1
        h = wave_sum_uniform(r_carry);
        if (lane == s - 1) outv = h;
        // step s: one fmaf from h, then exp2 (16 independent triples)
        float E[4][4];
#pragma unroll
        for (int g = 0; g < 4; ++g)
#pragma unroll
          for (int k = 0; k < 4; ++k)
            E[g][k] = fast_exp2(fmaf(h, whx[g][k], gx[g][k]));
        sched_fence();
        r_carry = combine(E);
      }
      h = wave_sum_uniform(r_carry);
      if (lane == CH - 1) outv = h;

      if (lane < CH)
        __hip_atomic_store(outp + c * CH + lane, outv, __ATOMIC_RELAXED,
                           __HIP_MEMORY_SCOPE_AGENT);
      if (lane == 0)
        __hip_atomic_store(my_flag, c + 1, __ATOMIC_RELEASE,
                           __HIP_MEMORY_SCOPE_AGENT);
    }
  } else {
    // ------------------------------------------------------------- MLP head
    // One wave per batch. Lane owns outputs o0 = lane and o1 = 64+lane (<100).
    __shared__ float hbuf[100];
    __shared__ float hbuf2[100];

    const int b = bid - LAYERS * BATCH;
    const float* h4 = seq + (4 * BATCH + b) * TT;
    const int* f4 = flags + 4 * BATCH + b;
    const int o0 = lane;
    const int o1 = 64 + lane;
    const bool has1 = (o1 < 100);

    float acc0 = 0.0f, acc1 = 0.0f;
    for (int c = 0; c < NCH; ++c) {
      while (__hip_atomic_load(f4, __ATOMIC_ACQUIRE,
                               __HIP_MEMORY_SCOPE_AGENT) <= c)
        __builtin_amdgcn_s_sleep(8);
      float xv = 0.0f;
      if (lane < CH)
        xv = __hip_atomic_load(h4 + c * CH + lane, __ATOMIC_RELAXED,
                               __HIP_MEMORY_SCOPE_AGENT);
      const float* w0 = W1 + o0 * TT + c * CH;
      const float* w1 = W1 + o1 * TT + c * CH;
#pragma unroll
      for (int j = 0; j < CH; j += 4) {
        float4 v0 = *(const float4*)(w0 + j);
        float x0 = lane_bcast(xv, j + 0);
        float x1 = lane_bcast(xv, j + 1);
        float x2 = lane_bcast(xv, j + 2);
        float x3 = lane_bcast(xv, j + 3);
        acc0 = fmaf(v0.x, x0, acc0);
        acc0 = fmaf(v0.y, x1, acc0);
        acc0 = fmaf(v0.z, x2, acc0);
        acc0 = fmaf(v0.w, x3, acc0);
        if (has1) {
          float4 v1 = *(const float4*)(w1 + j);
          acc1 = fmaf(v1.x, x0, acc1);
          acc1 = fmaf(v1.y, x1, acc1);
          acc1 = fmaf(v1.z, x2, acc1);
          acc1 = fmaf(v1.w, x3, acc1);
        }
      }
    }

    hbuf[o0] = fast_sigmoid(acc0 + b1[o0]);
    if (has1) hbuf[o1] = fast_sigmoid(acc1 + b1[o1]);
    __syncthreads();

    {  // layer 2
      float a0 = b2[o0], a1 = has1 ? b2[o1] : 0.0f;
      const float* w0r = W2 + o0 * 100;
      const float* w1r = W2 + o1 * 100;
      for (int k = 0; k < 100; ++k) {
        float hv = hbuf[k];
        a0 = fmaf(w0r[k], hv, a0);
        if (has1) a1 = fmaf(w1r[k], hv, a1);
      }
      hbuf2[o0] = fast_sigmoid(a0);
      if (has1) hbuf2[o1] = fast_sigmoid(a1);
    }
    __syncthreads();

    {  // layer 3 (relu)
      float a0 = b3[o0], a1 = has1 ? b3[o1] : 0.0f;
      const float* w0r = W3 + o0 * 100;
      const float* w1r = W3 + o1 * 100;
      for (int k = 0; k < 100; ++k) {
        float hv = hbuf2[k];
        a0 = fmaf(w0r[k], hv, a0);
        if (has1) a1 = fmaf(w1r[k], hv, a1);
      }
      hbuf[o0] = fmaxf(a0, 0.0f);
      if (has1) hbuf[o1] = fmaxf(a1, 0.0f);
    }
    __syncthreads();

    float r = hbuf[o0] * W4[o0] + (has1 ? hbuf[o1] * W4[o1] : 0.0f);
    r = wave_sum_uniform(r);
    if (lane == 0) out[b] = r + b4[0];
  }
}

extern "C" void kernel_launch(void* const* d_in, const int* in_sizes, int n_in,
                              void* d_out, int out_size, void* d_ws, size_t ws_size,
                              hipStream_t stream) {
  const float* x   = (const float*)d_in[0];
  const float* Wih = (const float*)d_in[1];
  const float* Whh = (const float*)d_in[2];
  const float* bih = (const float*)d_in[3];
  const float* bhh = (const float*)d_in[4];
  const float* Whr = (const float*)d_in[5];
  const float* W1  = (const float*)d_in[6];
  const float* b1  = (const float*)d_in[7];
  const float* W2  = (const float*)d_in[8];
  const float* b2  = (const float*)d_in[9];
  const float* W3  = (const float*)d_in[10];
  const float* b3  = (const float*)d_in[11];
  const float* W4  = (const float*)d_in[12];
  const float* b4  = (const float*)d_in[13];

  float* seq   = (float*)d_ws;                       // [5][128][1000] f32 = 2.56 MB
  int*   flags = (int*)(seq + LAYERS * BATCH * TT);  // [5][128] int

  hipMemsetAsync(flags, 0, LAYERS * BATCH * sizeof(int), stream);
  fused_pipeline_kernel<<<LAYERS * BATCH + BATCH, 64, 0, stream>>>(
      x, Wih, Whh, bih, bhh, Whr, W1, b1, W2, b2, W3, b3, W4, b4,
      seq, flags, (float*)d_out);
}